// Round 3
// baseline (26.048 us; speedup 1.0000x reference)
//
#include <hip/hip_runtime.h>

// WisePooling: ragged segment-mean over time axis + EPS.
// input: [B, T, D] float32, graph: [B, S, 2] int32 (start, end inclusive)
// output: [B, S, D] float32 = mean(input[b, start:end+1, :]) + EPS_ADD

#define EPS_ADD 0.006f

typedef float f4 __attribute__((ext_vector_type(4)));

// One block per (b, s) segment. 256 threads (R1 beat 512: occupancy was not
// the limiter). Per-thread: 4 independent accumulators + nontemporal float4
// loads -> deeper per-wave memory pipeline, no L2 pollution (stream has zero
// reuse; 134 MB through a 32 MB L2).
//   group g = tid & 63  -> float4 column group (D = 256 = 64 groups)
//   part  p = tid >> 6  -> row partition (4-way)
__global__ __launch_bounds__(256) void wise_pool_kernel(
    const float* __restrict__ x,   // [B, T, D]
    const int* __restrict__ graph, // [B, S, 2]
    float* __restrict__ out,       // [B, S, D]
    int B, int T, int D, int S)
{
    const int bs = blockIdx.x;        // 0 .. B*S-1
    const int b = bs / S;
    const int s = bs - b * S;

    const int start = graph[(b * S + s) * 2 + 0];
    const int end   = graph[(b * S + s) * 2 + 1];
    const int len   = end - start + 1;

    const int tid = threadIdx.x;
    const int g   = tid & 63;   // float4 group within row
    const int p   = tid >> 6;   // row partition 0..3

    const f4* xrow = reinterpret_cast<const f4*>(x + (size_t)b * T * D);
    const int groups = D >> 2;  // 64

    f4 a0 = (f4)0.f, a1 = (f4)0.f, a2 = (f4)0.f, a3 = (f4)0.f;

    int t = start + p;
    // Main: 4 rows per iteration (stride 16 across the 4-way partition),
    // 4 independent load->acc chains in flight.
    for (; t + 12 <= end; t += 16) {
        f4 v0 = __builtin_nontemporal_load(&xrow[(size_t)(t +  0) * groups + g]);
        f4 v1 = __builtin_nontemporal_load(&xrow[(size_t)(t +  4) * groups + g]);
        f4 v2 = __builtin_nontemporal_load(&xrow[(size_t)(t +  8) * groups + g]);
        f4 v3 = __builtin_nontemporal_load(&xrow[(size_t)(t + 12) * groups + g]);
        a0 += v0; a1 += v1; a2 += v2; a3 += v3;
    }
    // Ragged remainder.
    for (; t <= end; t += 4)
        a0 += __builtin_nontemporal_load(&xrow[(size_t)t * groups + g]);

    f4 acc = (a0 + a1) + (a2 + a3);

    __shared__ f4 sm[256];
    sm[tid] = acc;
    __syncthreads();

    if (p == 0) {
        f4 a = sm[g] + sm[g + 64] + sm[g + 128] + sm[g + 192];
        f4 r = a * (1.0f / (float)len) + EPS_ADD;
        reinterpret_cast<f4*>(out)[(size_t)bs * groups + g] = r;
    }
}

extern "C" void kernel_launch(void* const* d_in, const int* in_sizes, int n_in,
                              void* d_out, int out_size, void* d_ws, size_t ws_size,
                              hipStream_t stream) {
    const float* x     = (const float*)d_in[0];
    const int*   graph = (const int*)d_in[1];
    float*       out   = (float*)d_out;

    const int B = 16, T = 8192, D = 256, S = 64;
    dim3 grid(B * S);
    dim3 block(256);
    wise_pool_kernel<<<grid, block, 0, stream>>>(x, graph, out, B, T, D, S);
}

// Round 4
// 25.085 us; speedup vs baseline: 1.0384x; 1.0384x over previous
//
#include <hip/hip_runtime.h>

// WisePooling: ragged segment-mean over time axis + EPS.
// input: [B, T, D] float32, graph: [B, S, 2] int32 (start, end inclusive)
// output: [B, S, D] float32 = mean(input[b, start:end+1, :]) + EPS_ADD
//
// R1 (simple 256t) = 24.58us best. R2 (512t) = 25.41 (occupancy not limiter).
// R3 (nt + unroll4) = 26.05 (nt hint hurts). This round: R1 + unroll4
// WITHOUT nt + pointer-bump addressing — isolates memory-level parallelism
// from the nt cache hint.

#define EPS_ADD 0.006f

typedef float f4 __attribute__((ext_vector_type(4)));

__global__ __launch_bounds__(256) void wise_pool_kernel(
    const float* __restrict__ x,   // [B, T, D]
    const int* __restrict__ graph, // [B, S, 2]
    float* __restrict__ out,       // [B, S, D]
    int B, int T, int D, int S)
{
    const int bs = blockIdx.x;        // 0 .. B*S-1
    const int b = bs / S;
    const int s = bs - b * S;

    const int start = graph[(b * S + s) * 2 + 0];
    const int end   = graph[(b * S + s) * 2 + 1];
    const int len   = end - start + 1;

    const int tid = threadIdx.x;
    const int g   = tid & 63;   // float4 group within row (D=256 -> 64 groups)
    const int p   = tid >> 6;   // row partition 0..3

    const int groups = D >> 2;  // 64
    // Per-thread stream: rows start+p, start+p+4, ... each step = 4 rows
    // = 4*groups f4 = 4096 B. Pointer-bump, no per-iter 64-bit index mul.
    const f4* ptr = reinterpret_cast<const f4*>(x + (size_t)b * T * D)
                    + (size_t)(start + p) * groups + g;
    const ptrdiff_t step = (ptrdiff_t)4 * groups;   // one 4-row stride in f4s

    int remaining = (len - p + 3) >> 2;  // number of rows this thread owns

    f4 a0 = (f4)0.f, a1 = (f4)0.f, a2 = (f4)0.f, a3 = (f4)0.f;

    // 4 independent load->acc chains in flight (plain loads, no nt hint).
    while (remaining >= 4) {
        f4 v0 = ptr[0 * step];
        f4 v1 = ptr[1 * step];
        f4 v2 = ptr[2 * step];
        f4 v3 = ptr[3 * step];
        a0 += v0; a1 += v1; a2 += v2; a3 += v3;
        ptr += 4 * step;
        remaining -= 4;
    }
    while (remaining > 0) {
        a0 += ptr[0];
        ptr += step;
        --remaining;
    }

    f4 acc = (a0 + a1) + (a2 + a3);

    __shared__ f4 sm[256];
    sm[tid] = acc;
    __syncthreads();

    if (p == 0) {
        f4 a = sm[g] + sm[g + 64] + sm[g + 128] + sm[g + 192];
        f4 r = a * (1.0f / (float)len) + EPS_ADD;
        reinterpret_cast<f4*>(out)[(size_t)bs * groups + g] = r;
    }
}

extern "C" void kernel_launch(void* const* d_in, const int* in_sizes, int n_in,
                              void* d_out, int out_size, void* d_ws, size_t ws_size,
                              hipStream_t stream) {
    const float* x     = (const float*)d_in[0];
    const int*   graph = (const int*)d_in[1];
    float*       out   = (float*)d_out;

    const int B = 16, T = 8192, D = 256, S = 64;
    dim3 grid(B * S);
    dim3 block(256);
    wise_pool_kernel<<<grid, block, 0, stream>>>(x, graph, out, B, T, D, S);
}

// Round 5
// 24.641 us; speedup vs baseline: 1.0571x; 1.0180x over previous
//
#include <hip/hip_runtime.h>

// WisePooling: ragged segment-mean over time axis + EPS.
// input: [B, T, D] float32, graph: [B, S, 2] int32 (start, end inclusive)
// output: [B, S, D] float32 = mean(input[b, start:end+1, :]) + EPS_ADD
//
// Final configuration = R1 (measured best, 24.58us = 5.5 TB/s effective on
// the mandatory 134 MB read stream; ~87% of the 6.3 TB/s measured copy
// ceiling). Ablations: 512t/32-wave occupancy (R2) = -0.8us, nontemporal
// loads (R3) = -1.5us, 4-deep unroll + pointer-bump (R4) = -0.5us. The
// simple one-chain-per-lane 16-wave/CU version wins; read path saturated.

#define EPS_ADD 0.006f

// One block per (b, s) segment. 256 threads:
//   group g = tid & 63  -> float4 column group (D = 256 = 64 groups)
//   part  p = tid >> 6  -> row partition (4-way)
__global__ __launch_bounds__(256) void wise_pool_kernel(
    const float* __restrict__ x,   // [B, T, D]
    const int* __restrict__ graph, // [B, S, 2]
    float* __restrict__ out,       // [B, S, D]
    int B, int T, int D, int S)
{
    const int bs = blockIdx.x;        // 0 .. B*S-1
    const int b = bs / S;
    const int s = bs - b * S;

    const int start = graph[(b * S + s) * 2 + 0];
    const int end   = graph[(b * S + s) * 2 + 1];
    const int len   = end - start + 1;

    const int tid = threadIdx.x;
    const int g   = tid & 63;   // float4 group within row
    const int p   = tid >> 6;   // row partition 0..3

    const float4* xrow = reinterpret_cast<const float4*>(x + (size_t)b * T * D);
    const int groups = D >> 2;  // 64

    float4 acc = make_float4(0.f, 0.f, 0.f, 0.f);
    for (int t = start + p; t <= end; t += 4) {
        float4 v = xrow[(size_t)t * groups + g];
        acc.x += v.x; acc.y += v.y; acc.z += v.z; acc.w += v.w;
    }

    __shared__ float4 sm[256];
    sm[tid] = acc;
    __syncthreads();

    if (p == 0) {
        float4 a0 = sm[g];
        float4 a1 = sm[g + 64];
        float4 a2 = sm[g + 128];
        float4 a3 = sm[g + 192];
        float inv = 1.0f / (float)len;
        float4 r;
        r.x = (a0.x + a1.x + a2.x + a3.x) * inv + EPS_ADD;
        r.y = (a0.y + a1.y + a2.y + a3.y) * inv + EPS_ADD;
        r.z = (a0.z + a1.z + a2.z + a3.z) * inv + EPS_ADD;
        r.w = (a0.w + a1.w + a2.w + a3.w) * inv + EPS_ADD;
        reinterpret_cast<float4*>(out)[(size_t)bs * groups + g] = r;
    }
}

extern "C" void kernel_launch(void* const* d_in, const int* in_sizes, int n_in,
                              void* d_out, int out_size, void* d_ws, size_t ws_size,
                              hipStream_t stream) {
    const float* x     = (const float*)d_in[0];
    const int*   graph = (const int*)d_in[1];
    float*       out   = (float*)d_out;

    const int B = 16, T = 8192, D = 256, S = 64;
    dim3 grid(B * S);
    dim3 block(256);
    wise_pool_kernel<<<grid, block, 0, stream>>>(x, graph, out, B, T, D, S);
}